// Round 2
// baseline (430.599 us; speedup 1.0000x reference)
//
#include <hip/hip_runtime.h>

#define SQ 2048
#define DD 128
#define BHN 32                          // B*H = 2*16
// exp(s/sqrt(128)) == exp2(s * SC2)
#define SC2 0.12751741934f

typedef __attribute__((ext_vector_type(8))) short bf16x8;
typedef __attribute__((ext_vector_type(4))) float f32x4;

// f32 -> bf16 round-to-nearest-even
__device__ __forceinline__ unsigned short f2bf(float x){
  unsigned int u = __float_as_uint(x);
  unsigned int r = (u + 0x7FFFu + ((u >> 16) & 1u)) >> 16;
  return (unsigned short)r;
}
__device__ __forceinline__ unsigned pack2bf(float a, float b){
  return (unsigned)f2bf(a) | ((unsigned)f2bf(b) << 16);
}

// ---------------------------------------------------------------------------
// Kernel 1 (unchanged from R1, verified): quant-dequant K (per-token) and V
// (grouped-64), write bf16.
// dqK:  [bh][s][d] rows of 256B, bytes within row XOR-swizzled by (s&7)<<4.
// dqVt: [bh][d][s] rows of 4096B; within each aligned 128B block (64 tokens)
//       bytes XOR-swizzled by (d&7)<<4.
// ---------------------------------------------------------------------------
__global__ __launch_bounds__(256) void qd_kernel(const float* __restrict__ K,
                                                 const float* __restrict__ V,
                                                 char* __restrict__ dqK,
                                                 char* __restrict__ dqVt){
  __shared__ float Vlds[128*65];
  const int t = threadIdx.x;
  const int bh = blockIdx.x >> 5;
  const int stile = blockIdx.x & 31;
  const int tt = t >> 2;
  const int q4 = t & 3;
  const int s = stile*64 + tt;
  const long ebase = ((long)(bh*SQ + s))*DD + 32*q4;

  float vals[32];
  // ---- K: per-token absmax over 128 (4 lanes/token) ----
  {
    const float4* kp = (const float4*)(K + ebase);
    float am = 0.f;
    #pragma unroll
    for (int j=0;j<8;j++){
      float4 v4 = kp[j];
      vals[4*j+0]=v4.x; vals[4*j+1]=v4.y; vals[4*j+2]=v4.z; vals[4*j+3]=v4.w;
      am = fmaxf(am, fmaxf(fmaxf(fabsf(v4.x),fabsf(v4.y)),fmaxf(fabsf(v4.z),fabsf(v4.w))));
    }
    am = fmaxf(am, __shfl_xor(am,1));
    am = fmaxf(am, __shfl_xor(am,2));
    const float sc = fmaxf(am/7.0f, 1e-8f);
    #pragma unroll
    for (int j=0;j<32;j++){
      float qv = rintf(vals[j]/sc);
      qv = fminf(7.f, fmaxf(-7.f, qv));
      vals[j] = qv*sc;
    }
    const long rowb = ((long)(bh*SQ + s))*256;
    const int swz = (s & 7) << 4;
    #pragma unroll
    for (int c=0;c<4;c++){
      uint4 w;
      w.x = pack2bf(vals[8*c+0], vals[8*c+1]);
      w.y = pack2bf(vals[8*c+2], vals[8*c+3]);
      w.z = pack2bf(vals[8*c+4], vals[8*c+5]);
      w.w = pack2bf(vals[8*c+6], vals[8*c+7]);
      *(uint4*)(dqK + rowb + ((64*q4 + 16*c) ^ swz)) = w;
    }
  }
  // ---- V: grouped-64 absmax (2 lanes/group), dq into LDS transposed ----
  {
    const float4* vp = (const float4*)(V + ebase);
    float am = 0.f;
    #pragma unroll
    for (int j=0;j<8;j++){
      float4 v4 = vp[j];
      vals[4*j+0]=v4.x; vals[4*j+1]=v4.y; vals[4*j+2]=v4.z; vals[4*j+3]=v4.w;
      am = fmaxf(am, fmaxf(fmaxf(fabsf(v4.x),fabsf(v4.y)),fmaxf(fabsf(v4.z),fabsf(v4.w))));
    }
    am = fmaxf(am, __shfl_xor(am,1));
    const float sc = fmaxf(am/7.0f, 1e-8f);
    #pragma unroll
    for (int j=0;j<32;j++){
      float qv = rintf(vals[j]/sc);
      qv = fminf(7.f, fmaxf(-7.f, qv));
      Vlds[(32*q4 + j)*65 + tt] = qv*sc;
    }
  }
  __syncthreads();
  #pragma unroll
  for (int m=0;m<4;m++){
    const int chunk = m*256 + t;
    const int d = chunk >> 3;
    const int c = chunk & 7;
    uint4 w;
    const float* f = &Vlds[d*65 + 8*c];
    w.x = pack2bf(f[0], f[1]);
    w.y = pack2bf(f[2], f[3]);
    w.z = pack2bf(f[4], f[5]);
    w.w = pack2bf(f[6], f[7]);
    const long ob = ((long)(bh*DD + d))*4096 + (long)stile*128 + ((16*c) ^ ((d&7)<<4));
    *(uint4*)(dqVt + ob) = w;
  }
}

// ---------------------------------------------------------------------------
// Kernel 2: attention, barrier-free main loops.
// Block = (bh, 64 q-rows), 4 waves; wave w owns q-rows q0+16w..+15 in pass 1.
// Swapped QK^T: sacc = mfma(K_frag, Q_frag) -> S^T[token][q], lane l15 = q.
// E transpose via wave-private LDS (no __syncthreads in the k-loop).
// Pass 2: wave w handles k-tiles kt = w, w+4, ...; float4 weight stores.
// ---------------------------------------------------------------------------
__global__ __launch_bounds__(256) void attn_kernel(const float* __restrict__ Q,
    const char* __restrict__ dqK, const char* __restrict__ dqVt,
    float* __restrict__ Out, float* __restrict__ Wout){
  __shared__ __attribute__((aligned(16))) char Et[4][2048];  // wave-private 16x64 bf16
  __shared__ float Sinv[64];

  const int bid = blockIdx.x;
  const int xcd = bid & 7;                 // HW round-robin -> chunk bh per XCD
  const int loc = bid >> 3;                // 0..127
  const int bh  = xcd*4 + (loc >> 5);
  const int qt  = 31 - (loc & 31);         // heavy tiles first
  const int q0  = qt * 64;
  const int t = threadIdx.x;
  const int lane = t & 63;
  const int w = t >> 6;
  const int l15 = lane & 15, l4 = lane >> 4;
  const int swz = (l15 & 7) << 4;
  const int qrow = q0 + 16*w + l15;

  // Q B-fragments: lane l15 = q-row (n), elems d = 32*kk + 8*l4 + j
  bf16x8 qa[4];
  {
    const float* qb = Q + ((long)(bh*SQ) + qrow)*DD + 8*l4;
    #pragma unroll
    for (int kk=0;kk<4;kk++){
      float4 a = *(const float4*)(qb + 32*kk);
      float4 b = *(const float4*)(qb + 32*kk + 4);
      bf16x8 r;
      r[0]=(short)f2bf(a.x); r[1]=(short)f2bf(a.y); r[2]=(short)f2bf(a.z); r[3]=(short)f2bf(a.w);
      r[4]=(short)f2bf(b.x); r[5]=(short)f2bf(b.y); r[6]=(short)f2bf(b.z); r[7]=(short)f2bf(b.w);
      qa[kk]=r;
    }
  }

  const char* Kb = dqK + (long)bh*SQ*256;
  const char* Vb = dqVt + (long)bh*DD*4096;
  const int nkt = qt + 1;

  const f32x4 z4 = {0.f,0.f,0.f,0.f};
  f32x4 oacc[8] = {z4,z4,z4,z4,z4,z4,z4,z4};
  float ssum = 0.f;
  char* eb = &Et[w][0];

  for (int kt=0; kt<nkt; ++kt){
    const int k0 = kt*64;
    // --- QK^T swapped: sacc[cf] = S^T tile [16 tokens][16 q] ---
    f32x4 sacc[4] = {z4,z4,z4,z4};
    {
      const char* kr = Kb + (long)k0*256 + l15*256;
      #pragma unroll
      for (int cf=0;cf<4;cf++){
        #pragma unroll
        for (int kk=0;kk<4;kk++){
          bf16x8 kb = *(const bf16x8*)(kr + cf*4096 + ((64*kk+16*l4) ^ swz));
          sacc[cf] = __builtin_amdgcn_mfma_f32_16x16x32_bf16(kb, qa[kk], sacc[cf], 0,0,0);
        }
      }
    }
    // --- V B-fragments for this k-tile (lane l15 = d) ---
    bf16x8 vb[8][2];
    {
      const char* vr = Vb + (long)l15*4096 + k0*2;
      #pragma unroll
      for (int df=0;df<8;df++){
        const char* vrow = vr + (long)df*(16*4096);
        vb[df][0] = *(const bf16x8*)(vrow + ((16*l4) ^ swz));
        vb[df][1] = *(const bf16x8*)(vrow + ((64 + 16*l4) ^ swz));
      }
    }
    // --- exp + causal mask -> Et (bf16, wave-private, XOR-swizzled) ---
    #pragma unroll
    for (int cf=0;cf<4;cf++){
      const int tok0 = k0 + 16*cf + 4*l4;
      float e0 = (tok0+0 <= qrow) ? exp2f(sacc[cf][0]*SC2) : 0.f;
      float e1 = (tok0+1 <= qrow) ? exp2f(sacc[cf][1]*SC2) : 0.f;
      float e2 = (tok0+2 <= qrow) ? exp2f(sacc[cf][2]*SC2) : 0.f;
      float e3 = (tok0+3 <= qrow) ? exp2f(sacc[cf][3]*SC2) : 0.f;
      ssum += (e0+e1) + (e2+e3);
      uint2 wp; wp.x = pack2bf(e0,e1); wp.y = pack2bf(e2,e3);
      *(uint2*)(eb + l15*128 + ((32*cf + 8*l4) ^ swz)) = wp;
    }
    // --- PV: A = E rows (lane l15 = q), B = V ---
    #pragma unroll
    for (int kc=0;kc<2;kc++){
      bf16x8 ea = *(const bf16x8*)(eb + l15*128 + ((64*kc + 16*l4) ^ swz));
      #pragma unroll
      for (int df=0;df<8;df++)
        oacc[df] = __builtin_amdgcn_mfma_f32_16x16x32_bf16(ea, vb[df][kc], oacc[df], 0,0,0);
    }
  }

  // row sums: lanes sharing l15 hold partials for q = qrow
  float s = ssum;
  s += __shfl_xor(s, 16);
  s += __shfl_xor(s, 32);
  const float sinv = 1.0f / s;
  if (l4 == 0) Sinv[w*16 + l15] = sinv;

  // O write: C rows m = 4*l4+i (q-idx), cols 16*df+l15 (d)
  float invr[4];
  #pragma unroll
  for (int i=0;i<4;i++) invr[i] = __shfl(sinv, 4*l4+i);
  {
    float* ob = Out + ((long)(bh*SQ) + q0 + 16*w)*DD;
    #pragma unroll
    for (int df=0;df<8;df++){
      #pragma unroll
      for (int i=0;i<4;i++)
        ob[(4*l4+i)*DD + 16*df + l15] = oacc[df][i]*invr[i];
    }
  }

  __syncthreads();   // Sinv ready for all waves

  // ---- pass 2: normalized weights; wave w takes k-tiles w, w+4, ... ----
  bf16x8 qg[4][4];   // Q frags for all 4 q-groups of the block
  #pragma unroll
  for (int g=0; g<4; ++g){
    const float* qb = Q + ((long)(bh*SQ) + q0 + 16*g + l15)*DD + 8*l4;
    #pragma unroll
    for (int kk=0;kk<4;kk++){
      float4 a = *(const float4*)(qb + 32*kk);
      float4 b = *(const float4*)(qb + 32*kk + 4);
      bf16x8 r;
      r[0]=(short)f2bf(a.x); r[1]=(short)f2bf(a.y); r[2]=(short)f2bf(a.z); r[3]=(short)f2bf(a.w);
      r[4]=(short)f2bf(b.x); r[5]=(short)f2bf(b.y); r[6]=(short)f2bf(b.z); r[7]=(short)f2bf(b.w);
      qg[g][kk]=r;
    }
  }
  float si[4];
  #pragma unroll
  for (int g=0; g<4; ++g) si[g] = Sinv[g*16 + l15];

  float* Wbase = Wout + (long)bh*SQ*SQ;
  for (int kt=w; kt<nkt; kt+=4){
    const int k0 = kt*64;
    const char* kr = Kb + (long)k0*256 + l15*256;
    #pragma unroll
    for (int cf=0;cf<4;cf++){
      bf16x8 kb[4];
      #pragma unroll
      for (int kk=0;kk<4;kk++)
        kb[kk] = *(const bf16x8*)(kr + cf*4096 + ((64*kk+16*l4) ^ swz));
      const int tok0 = k0 + 16*cf + 4*l4;
      #pragma unroll
      for (int g=0; g<4; ++g){
        f32x4 acc = z4;
        #pragma unroll
        for (int kk=0;kk<4;kk++)
          acc = __builtin_amdgcn_mfma_f32_16x16x32_bf16(kb[kk], qg[g][kk], acc, 0,0,0);
        const int qr = q0 + 16*g + l15;
        float4 wv;
        wv.x = (tok0+0 <= qr) ? exp2f(acc[0]*SC2)*si[g] : 0.f;
        wv.y = (tok0+1 <= qr) ? exp2f(acc[1]*SC2)*si[g] : 0.f;
        wv.z = (tok0+2 <= qr) ? exp2f(acc[2]*SC2)*si[g] : 0.f;
        wv.w = (tok0+3 <= qr) ? exp2f(acc[3]*SC2)*si[g] : 0.f;
        *(float4*)(Wbase + (long)qr*SQ + tok0) = wv;
      }
    }
  }

  // zero-fill fully-masked columns [nkt*64, 2048); wave w -> its 16 rows
  const int z0 = nkt*64;
  if (z0 < SQ){
    float* wr = Wbase + (long)(q0 + 16*w)*SQ;
    const float4 zz = {0.f,0.f,0.f,0.f};
    for (int r=0;r<16;r++){
      float* row = wr + (long)r*SQ;
      for (int c = z0 + 4*lane; c < SQ; c += 256)
        *(float4*)(row + c) = zz;
    }
  }
}

extern "C" void kernel_launch(void* const* d_in, const int* in_sizes, int n_in,
                              void* d_out, int out_size, void* d_ws, size_t ws_size,
                              hipStream_t stream) {
  const float* Q = (const float*)d_in[0];
  const float* K = (const float*)d_in[1];
  const float* V = (const float*)d_in[2];
  float* Out = (float*)d_out;
  float* Wout = (float*)d_out + (size_t)BHN*SQ*DD;
  char* dqK  = (char*)d_ws;                               // 16 MB
  char* dqVt = (char*)d_ws + (size_t)BHN*SQ*DD*2;         // 16 MB

  qd_kernel<<<BHN*32, 256, 0, stream>>>(K, V, dqK, dqVt);
  attn_kernel<<<BHN*32, 256, 0, stream>>>(Q, dqK, dqVt, Out, Wout);
}

// Round 3
// 307.150 us; speedup vs baseline: 1.4019x; 1.4019x over previous
//
#include <hip/hip_runtime.h>

#define SQ 2048
#define DD 128
#define BHN 32                          // B*H = 2*16
// exp(s/sqrt(128)) == exp2(s * SC2)
#define SC2 0.12751741934f

typedef __attribute__((ext_vector_type(8))) short bf16x8;
typedef __attribute__((ext_vector_type(4))) float f32x4;

// f32 -> bf16 round-to-nearest-even
__device__ __forceinline__ unsigned short f2bf(float x){
  unsigned int u = __float_as_uint(x);
  unsigned int r = (u + 0x7FFFu + ((u >> 16) & 1u)) >> 16;
  return (unsigned short)r;
}
__device__ __forceinline__ unsigned pack2bf(float a, float b){
  return (unsigned)f2bf(a) | ((unsigned)f2bf(b) << 16);
}

// async 16B global->LDS (dest = wave-uniform base + lane*16, linear)
__device__ __forceinline__ void gl_lds16(const void* g, void* l){
  __builtin_amdgcn_global_load_lds(
      (const __attribute__((address_space(1))) unsigned int*)g,
      (__attribute__((address_space(3))) unsigned int*)l, 16, 0, 0);
}

// ---------------------------------------------------------------------------
// Kernel 1 (verified R1/R2): quant-dequant K (per-token) and V (grouped-64).
// dqK:  [bh][s][d] rows of 256B, bytes within row XOR-swizzled by (s&7)<<4.
// dqVt: [bh][d][s] rows of 4096B; within each aligned 128B block (64 tokens)
//       bytes XOR-swizzled by (d&7)<<4.
// ---------------------------------------------------------------------------
__global__ __launch_bounds__(256) void qd_kernel(const float* __restrict__ K,
                                                 const float* __restrict__ V,
                                                 char* __restrict__ dqK,
                                                 char* __restrict__ dqVt){
  __shared__ float Vlds[128*65];
  const int t = threadIdx.x;
  const int bh = blockIdx.x >> 5;
  const int stile = blockIdx.x & 31;
  const int tt = t >> 2;
  const int q4 = t & 3;
  const int s = stile*64 + tt;
  const long ebase = ((long)(bh*SQ + s))*DD + 32*q4;

  float vals[32];
  {
    const float4* kp = (const float4*)(K + ebase);
    float am = 0.f;
    #pragma unroll
    for (int j=0;j<8;j++){
      float4 v4 = kp[j];
      vals[4*j+0]=v4.x; vals[4*j+1]=v4.y; vals[4*j+2]=v4.z; vals[4*j+3]=v4.w;
      am = fmaxf(am, fmaxf(fmaxf(fabsf(v4.x),fabsf(v4.y)),fmaxf(fabsf(v4.z),fabsf(v4.w))));
    }
    am = fmaxf(am, __shfl_xor(am,1));
    am = fmaxf(am, __shfl_xor(am,2));
    const float sc = fmaxf(am/7.0f, 1e-8f);
    #pragma unroll
    for (int j=0;j<32;j++){
      float qv = rintf(vals[j]/sc);
      qv = fminf(7.f, fmaxf(-7.f, qv));
      vals[j] = qv*sc;
    }
    const long rowb = ((long)(bh*SQ + s))*256;
    const int swz = (s & 7) << 4;
    #pragma unroll
    for (int c=0;c<4;c++){
      uint4 w;
      w.x = pack2bf(vals[8*c+0], vals[8*c+1]);
      w.y = pack2bf(vals[8*c+2], vals[8*c+3]);
      w.z = pack2bf(vals[8*c+4], vals[8*c+5]);
      w.w = pack2bf(vals[8*c+6], vals[8*c+7]);
      *(uint4*)(dqK + rowb + ((64*q4 + 16*c) ^ swz)) = w;
    }
  }
  {
    const float4* vp = (const float4*)(V + ebase);
    float am = 0.f;
    #pragma unroll
    for (int j=0;j<8;j++){
      float4 v4 = vp[j];
      vals[4*j+0]=v4.x; vals[4*j+1]=v4.y; vals[4*j+2]=v4.z; vals[4*j+3]=v4.w;
      am = fmaxf(am, fmaxf(fmaxf(fabsf(v4.x),fabsf(v4.y)),fmaxf(fabsf(v4.z),fabsf(v4.w))));
    }
    am = fmaxf(am, __shfl_xor(am,1));
    const float sc = fmaxf(am/7.0f, 1e-8f);
    #pragma unroll
    for (int j=0;j<32;j++){
      float qv = rintf(vals[j]/sc);
      qv = fminf(7.f, fmaxf(-7.f, qv));
      Vlds[(32*q4 + j)*65 + tt] = qv*sc;
    }
  }
  __syncthreads();
  #pragma unroll
  for (int m=0;m<4;m++){
    const int chunk = m*256 + t;
    const int d = chunk >> 3;
    const int c = chunk & 7;
    uint4 w;
    const float* f = &Vlds[d*65 + 8*c];
    w.x = pack2bf(f[0], f[1]);
    w.y = pack2bf(f[2], f[3]);
    w.z = pack2bf(f[4], f[5]);
    w.w = pack2bf(f[6], f[7]);
    const long ob = ((long)(bh*DD + d))*4096 + (long)stile*128 + ((16*c) ^ ((d&7)<<4));
    *(uint4*)(dqVt + ob) = w;
  }
}

// ---------------------------------------------------------------------------
// Pass 1: O + row-sums. Block = (bh, 128 q-rows), 8 waves, wave w owns rows
// q0+16w..+15. LDS-staged K (16KB) + V^T (16KB), double-buffered, one
// __syncthreads per k-tile (stage of kt+1 issued before compute of kt).
// Swapped QK^T (mfma(K,Q) -> S^T, lane l15 = q); E transpose wave-private.
// ---------------------------------------------------------------------------
__global__ __launch_bounds__(512,4) void attn1_kernel(const float* __restrict__ Q,
    const char* __restrict__ dqK, const char* __restrict__ dqVt,
    float* __restrict__ Out, float* __restrict__ SinvG){
  __shared__ __attribute__((aligned(16))) char Kt[2][16384];
  __shared__ __attribute__((aligned(16))) char Vt[2][16384];
  __shared__ __attribute__((aligned(16))) char Et[8][2048];

  const int bid = blockIdx.x;
  const int xcd = bid & 7;                 // chunk bh per XCD for L2 locality
  const int loc = bid >> 3;                // 0..63
  const int bh  = xcd*4 + (loc >> 4);
  const int qi  = loc & 15;
  const int qt  = (qi & 1) ? (qi >> 1) : (15 - (qi >> 1));  // heavy/light pairs
  const int q0  = qt * 128;
  const int t = threadIdx.x;
  const int lane = t & 63;
  const int w = t >> 6;
  const int l15 = lane & 15, l4 = lane >> 4;
  const int swz = (l15 & 7) << 4;
  const int qrow = q0 + 16*w + l15;

  // Q B-fragments: lane l15 = q-row (n), elems d = 32*kk + 8*l4 + j
  bf16x8 qa[4];
  {
    const float* qb = Q + ((long)(bh*SQ) + qrow)*DD + 8*l4;
    #pragma unroll
    for (int kk=0;kk<4;kk++){
      float4 a = *(const float4*)(qb + 32*kk);
      float4 b = *(const float4*)(qb + 32*kk + 4);
      bf16x8 r;
      r[0]=(short)f2bf(a.x); r[1]=(short)f2bf(a.y); r[2]=(short)f2bf(a.z); r[3]=(short)f2bf(a.w);
      r[4]=(short)f2bf(b.x); r[5]=(short)f2bf(b.y); r[6]=(short)f2bf(b.z); r[7]=(short)f2bf(b.w);
      qa[kk]=r;
    }
  }

  const char* Kb = dqK + (long)bh*SQ*256;
  const char* Vb = dqVt + (long)bh*DD*4096;
  const int nkt = 2*qt + 2;

  const f32x4 z4 = {0.f,0.f,0.f,0.f};
  f32x4 oacc[8] = {z4,z4,z4,z4,z4,z4,z4,z4};
  float ssum = 0.f;
  char* eb = &Et[w][0];

  // stage one k-tile (K 16KB linear + V^T 128 rows x 128B) into buffer `buf`
  auto stage = [&](int buf, int kt){
    const char* ks = Kb + (long)kt*16384;
    gl_lds16(ks + t*16,        &Kt[buf][t*16]);
    gl_lds16(ks + 8192 + t*16, &Kt[buf][8192 + t*16]);
    const char* vs = Vb + (long)kt*128;
    gl_lds16(vs + (long)(t>>3)*4096      + (t&7)*16, &Vt[buf][t*16]);
    gl_lds16(vs + (long)(64+(t>>3))*4096 + (t&7)*16, &Vt[buf][8192 + t*16]);
  };

  stage(0, 0);
  __syncthreads();
  int cur = 0;
  for (int kt=0; kt<nkt; ++kt){
    if (kt+1 < nkt) stage(cur^1, kt+1);   // overlap with compute below
    const int k0 = kt*64;

    // --- QK^T swapped: sacc[cf] = S^T [16 tokens][16 q] ---
    f32x4 sacc[4] = {z4,z4,z4,z4};
    {
      const char* kbase = &Kt[cur][0] + l15*256;
      __builtin_amdgcn_s_setprio(1);
      #pragma unroll
      for (int cf=0;cf<4;cf++){
        #pragma unroll
        for (int kk=0;kk<4;kk++){
          bf16x8 kb = *(const bf16x8*)(kbase + cf*4096 + ((64*kk+16*l4) ^ swz));
          sacc[cf] = __builtin_amdgcn_mfma_f32_16x16x32_bf16(kb, qa[kk], sacc[cf], 0,0,0);
        }
      }
      __builtin_amdgcn_s_setprio(0);
    }

    // --- exp (+mask on the 2 boundary tiles) -> Et (bf16, wave-private) ---
    if (kt < 2*qt){
      #pragma unroll
      for (int cf=0;cf<4;cf++){
        float e0 = exp2f(sacc[cf][0]*SC2);
        float e1 = exp2f(sacc[cf][1]*SC2);
        float e2 = exp2f(sacc[cf][2]*SC2);
        float e3 = exp2f(sacc[cf][3]*SC2);
        ssum += (e0+e1) + (e2+e3);
        uint2 wp; wp.x = pack2bf(e0,e1); wp.y = pack2bf(e2,e3);
        *(uint2*)(eb + l15*128 + ((32*cf + 8*l4) ^ swz)) = wp;
      }
    } else {
      #pragma unroll
      for (int cf=0;cf<4;cf++){
        const int tok0 = k0 + 16*cf + 4*l4;
        float e0 = (tok0+0 <= qrow) ? exp2f(sacc[cf][0]*SC2) : 0.f;
        float e1 = (tok0+1 <= qrow) ? exp2f(sacc[cf][1]*SC2) : 0.f;
        float e2 = (tok0+2 <= qrow) ? exp2f(sacc[cf][2]*SC2) : 0.f;
        float e3 = (tok0+3 <= qrow) ? exp2f(sacc[cf][3]*SC2) : 0.f;
        ssum += (e0+e1) + (e2+e3);
        uint2 wp; wp.x = pack2bf(e0,e1); wp.y = pack2bf(e2,e3);
        *(uint2*)(eb + l15*128 + ((32*cf + 8*l4) ^ swz)) = wp;
      }
    }

    // --- PV: A = E rows (lane l15 = q), B = V^T from LDS ---
    {
      const char* vbase = &Vt[cur][0] + l15*128;
      __builtin_amdgcn_s_setprio(1);
      #pragma unroll
      for (int kc=0;kc<2;kc++){
        bf16x8 ea = *(const bf16x8*)(eb + l15*128 + ((64*kc + 16*l4) ^ swz));
        #pragma unroll
        for (int df=0;df<8;df++){
          bf16x8 vv = *(const bf16x8*)(vbase + df*2048 + ((64*kc + 16*l4) ^ swz));
          oacc[df] = __builtin_amdgcn_mfma_f32_16x16x32_bf16(ea, vv, oacc[df], 0,0,0);
        }
      }
      __builtin_amdgcn_s_setprio(0);
    }
    __syncthreads();   // drains next-tile stage (vmcnt 0) + protects buffers
    cur ^= 1;
  }

  // row sums: lanes sharing l15 hold partials for q = qrow
  float s = ssum;
  s += __shfl_xor(s, 16);
  s += __shfl_xor(s, 32);
  const float sinv = 1.0f / s;
  if (l4 == 0) SinvG[(long)bh*SQ + qrow] = sinv;

  float invr[4];
  #pragma unroll
  for (int i=0;i<4;i++) invr[i] = __shfl(sinv, 4*l4+i);
  {
    float* ob = Out + ((long)(bh*SQ) + q0 + 16*w)*DD;
    #pragma unroll
    for (int df=0;df<8;df++){
      #pragma unroll
      for (int i=0;i<4;i++)
        ob[(4*l4+i)*DD + 16*df + l15] = oacc[df][i]*invr[i];
    }
  }
}

// ---------------------------------------------------------------------------
// Pass 2: weights = exp(S)/l (recompute QK^T), uniform write-bound blocks.
// Block = (bh, 64 q-rows), 4 waves, wave w owns rows q0+16w..+15.
// K staged in LDS double-buffered; float4 stores; zero-fill masked region.
// ---------------------------------------------------------------------------
__global__ __launch_bounds__(256) void attn2_kernel(const float* __restrict__ Q,
    const char* __restrict__ dqK, const float* __restrict__ SinvG,
    float* __restrict__ Wout){
  __shared__ __attribute__((aligned(16))) char Kt[2][16384];

  const int bid = blockIdx.x;
  const int xcd = bid & 7;
  const int loc = bid >> 3;           // 0..127
  const int bh  = xcd*4 + (loc >> 5);
  const int qt  = loc & 31;
  const int q0  = qt * 64;
  const int t = threadIdx.x;
  const int lane = t & 63;
  const int w = t >> 6;
  const int l15 = lane & 15, l4 = lane >> 4;
  const int swz = (l15 & 7) << 4;
  const int qrow = q0 + 16*w + l15;

  bf16x8 qa[4];
  {
    const float* qb = Q + ((long)(bh*SQ) + qrow)*DD + 8*l4;
    #pragma unroll
    for (int kk=0;kk<4;kk++){
      float4 a = *(const float4*)(qb + 32*kk);
      float4 b = *(const float4*)(qb + 32*kk + 4);
      bf16x8 r;
      r[0]=(short)f2bf(a.x); r[1]=(short)f2bf(a.y); r[2]=(short)f2bf(a.z); r[3]=(short)f2bf(a.w);
      r[4]=(short)f2bf(b.x); r[5]=(short)f2bf(b.y); r[6]=(short)f2bf(b.z); r[7]=(short)f2bf(b.w);
      qa[kk]=r;
    }
  }
  const float si = SinvG[(long)bh*SQ + qrow];
  const char* Kb = dqK + (long)bh*SQ*256;
  const int nkt = qt + 1;
  float* Wbase = Wout + (long)bh*SQ*SQ;
  float* wrow  = Wbase + (long)qrow*SQ;

  auto stage = [&](int buf, int kt){
    const char* ks = Kb + (long)kt*16384;
    #pragma unroll
    for (int i=0;i<4;i++)
      gl_lds16(ks + i*4096 + t*16, &Kt[buf][i*4096 + t*16]);
  };

  stage(0,0);
  __syncthreads();
  int cur = 0;
  const f32x4 z4 = {0.f,0.f,0.f,0.f};
  for (int kt=0; kt<nkt; ++kt){
    if (kt+1 < nkt) stage(cur^1, kt+1);
    const int k0 = kt*64;

    f32x4 sacc[4] = {z4,z4,z4,z4};
    {
      const char* kbase = &Kt[cur][0] + l15*256;
      __builtin_amdgcn_s_setprio(1);
      #pragma unroll
      for (int cf=0;cf<4;cf++){
        #pragma unroll
        for (int kk=0;kk<4;kk++){
          bf16x8 kb = *(const bf16x8*)(kbase + cf*4096 + ((64*kk+16*l4) ^ swz));
          sacc[cf] = __builtin_amdgcn_mfma_f32_16x16x32_bf16(kb, qa[kk], sacc[cf], 0,0,0);
        }
      }
      __builtin_amdgcn_s_setprio(0);
    }

    if (kt < qt){   // full tile
      #pragma unroll
      for (int cf=0;cf<4;cf++){
        const int tok0 = k0 + 16*cf + 4*l4;
        float4 wv;
        wv.x = exp2f(sacc[cf][0]*SC2)*si;
        wv.y = exp2f(sacc[cf][1]*SC2)*si;
        wv.z = exp2f(sacc[cf][2]*SC2)*si;
        wv.w = exp2f(sacc[cf][3]*SC2)*si;
        *(float4*)(wrow + tok0) = wv;
      }
    } else {        // diagonal tile
      #pragma unroll
      for (int cf=0;cf<4;cf++){
        const int tok0 = k0 + 16*cf + 4*l4;
        float4 wv;
        wv.x = (tok0+0 <= qrow) ? exp2f(sacc[cf][0]*SC2)*si : 0.f;
        wv.y = (tok0+1 <= qrow) ? exp2f(sacc[cf][1]*SC2)*si : 0.f;
        wv.z = (tok0+2 <= qrow) ? exp2f(sacc[cf][2]*SC2)*si : 0.f;
        wv.w = (tok0+3 <= qrow) ? exp2f(sacc[cf][3]*SC2)*si : 0.f;
        *(float4*)(wrow + tok0) = wv;
      }
    }
    __syncthreads();
    cur ^= 1;
  }

  // zero-fill fully-masked columns [nkt*64, 2048)
  const int z0 = nkt*64;
  if (z0 < SQ){
    float* wr = Wbase + (long)(q0 + 16*w)*SQ;
    const float4 zz = {0.f,0.f,0.f,0.f};
    for (int r=0;r<16;r++){
      float* row = wr + (long)r*SQ;
      for (int c = z0 + 4*lane; c < SQ; c += 256)
        *(float4*)(row + c) = zz;
    }
  }
}

extern "C" void kernel_launch(void* const* d_in, const int* in_sizes, int n_in,
                              void* d_out, int out_size, void* d_ws, size_t ws_size,
                              hipStream_t stream) {
  const float* Q = (const float*)d_in[0];
  const float* K = (const float*)d_in[1];
  const float* V = (const float*)d_in[2];
  float* Out = (float*)d_out;
  float* Wout = (float*)d_out + (size_t)BHN*SQ*DD;
  char* dqK  = (char*)d_ws;                                // 16 MB
  char* dqVt = (char*)d_ws + (size_t)BHN*SQ*DD*2;          // 16 MB
  float* SinvG = (float*)((char*)d_ws + (size_t)BHN*SQ*DD*4);  // 256 KB @ +32MB

  qd_kernel<<<BHN*32, 256, 0, stream>>>(K, V, dqK, dqVt);
  attn1_kernel<<<512, 512, 0, stream>>>(Q, dqK, dqVt, Out, SinvG);
  attn2_kernel<<<1024, 256, 0, stream>>>(Q, dqK, SinvG, Wout);
}

// Round 4
// 280.914 us; speedup vs baseline: 1.5329x; 1.0934x over previous
//
#include <hip/hip_runtime.h>

#define SQ 2048
#define DD 128
#define BHN 32                          // B*H = 2*16
// exp(s/sqrt(128)) == exp2(s * SC2)
#define SC2 0.12751741934f

typedef __attribute__((ext_vector_type(8))) short bf16x8;
typedef __attribute__((ext_vector_type(4))) float f32x4;

// f32 -> bf16 round-to-nearest-even
__device__ __forceinline__ unsigned short f2bf(float x){
  unsigned int u = __float_as_uint(x);
  unsigned int r = (u + 0x7FFFu + ((u >> 16) & 1u)) >> 16;
  return (unsigned short)r;
}
__device__ __forceinline__ unsigned pack2bf(float a, float b){
  return (unsigned)f2bf(a) | ((unsigned)f2bf(b) << 16);
}

// async 16B global->LDS (dest = wave-uniform base + lane*16, linear)
__device__ __forceinline__ void gl_lds16(const void* g, void* l){
  __builtin_amdgcn_global_load_lds(
      (const __attribute__((address_space(1))) unsigned int*)g,
      (__attribute__((address_space(3))) unsigned int*)l, 16, 0, 0);
}

// ---------------------------------------------------------------------------
// Kernel 1 (verified R1-R3): quant-dequant K (per-token) and V (grouped-64).
// dqK:  [bh][s][d] rows of 256B, bytes within row XOR-swizzled by (s&7)<<4.
// dqVt: [bh][d][s] rows of 4096B; within each aligned 128B block (64 tokens)
//       bytes XOR-swizzled by (d&7)<<4.
// ---------------------------------------------------------------------------
__global__ __launch_bounds__(256) void qd_kernel(const float* __restrict__ K,
                                                 const float* __restrict__ V,
                                                 char* __restrict__ dqK,
                                                 char* __restrict__ dqVt){
  __shared__ float Vlds[128*65];
  const int t = threadIdx.x;
  const int bh = blockIdx.x >> 5;
  const int stile = blockIdx.x & 31;
  const int tt = t >> 2;
  const int q4 = t & 3;
  const int s = stile*64 + tt;
  const long ebase = ((long)(bh*SQ + s))*DD + 32*q4;

  float vals[32];
  {
    const float4* kp = (const float4*)(K + ebase);
    float am = 0.f;
    #pragma unroll
    for (int j=0;j<8;j++){
      float4 v4 = kp[j];
      vals[4*j+0]=v4.x; vals[4*j+1]=v4.y; vals[4*j+2]=v4.z; vals[4*j+3]=v4.w;
      am = fmaxf(am, fmaxf(fmaxf(fabsf(v4.x),fabsf(v4.y)),fmaxf(fabsf(v4.z),fabsf(v4.w))));
    }
    am = fmaxf(am, __shfl_xor(am,1));
    am = fmaxf(am, __shfl_xor(am,2));
    const float sc = fmaxf(am/7.0f, 1e-8f);
    #pragma unroll
    for (int j=0;j<32;j++){
      float qv = rintf(vals[j]/sc);
      qv = fminf(7.f, fmaxf(-7.f, qv));
      vals[j] = qv*sc;
    }
    const long rowb = ((long)(bh*SQ + s))*256;
    const int swz = (s & 7) << 4;
    #pragma unroll
    for (int c=0;c<4;c++){
      uint4 w;
      w.x = pack2bf(vals[8*c+0], vals[8*c+1]);
      w.y = pack2bf(vals[8*c+2], vals[8*c+3]);
      w.z = pack2bf(vals[8*c+4], vals[8*c+5]);
      w.w = pack2bf(vals[8*c+6], vals[8*c+7]);
      *(uint4*)(dqK + rowb + ((64*q4 + 16*c) ^ swz)) = w;
    }
  }
  {
    const float4* vp = (const float4*)(V + ebase);
    float am = 0.f;
    #pragma unroll
    for (int j=0;j<8;j++){
      float4 v4 = vp[j];
      vals[4*j+0]=v4.x; vals[4*j+1]=v4.y; vals[4*j+2]=v4.z; vals[4*j+3]=v4.w;
      am = fmaxf(am, fmaxf(fmaxf(fabsf(v4.x),fabsf(v4.y)),fmaxf(fabsf(v4.z),fabsf(v4.w))));
    }
    am = fmaxf(am, __shfl_xor(am,1));
    const float sc = fmaxf(am/7.0f, 1e-8f);
    #pragma unroll
    for (int j=0;j<32;j++){
      float qv = rintf(vals[j]/sc);
      qv = fminf(7.f, fmaxf(-7.f, qv));
      Vlds[(32*q4 + j)*65 + tt] = qv*sc;
    }
  }
  __syncthreads();
  #pragma unroll
  for (int m=0;m<4;m++){
    const int chunk = m*256 + t;
    const int d = chunk >> 3;
    const int c = chunk & 7;
    uint4 w;
    const float* f = &Vlds[d*65 + 8*c];
    w.x = pack2bf(f[0], f[1]);
    w.y = pack2bf(f[2], f[3]);
    w.z = pack2bf(f[4], f[5]);
    w.w = pack2bf(f[6], f[7]);
    const long ob = ((long)(bh*DD + d))*4096 + (long)stile*128 + ((16*c) ^ ((d&7)<<4));
    *(uint4*)(dqVt + ob) = w;
  }
}

// ---------------------------------------------------------------------------
// Pass 1: O + row-sums. 256 blocks (1/CU), 8 waves, 96KB LDS.
// Waves 0-3: strip A (qt=15-p, 128 rows), waves 4-7: strip B (qt=p).
// Joint k-loop over nktA tiles; B-waves compute only while kt<nktB; every
// block does nktA+nktB = 34 compute-units -> uniform work.
// Each wave owns 32 q-rows (2 MFMA row-groups) -> K/V LDS reads amortized 2x.
// ---------------------------------------------------------------------------
__global__ __launch_bounds__(512,2) void attn1_kernel(const float* __restrict__ Q,
    const char* __restrict__ dqK, const char* __restrict__ dqVt,
    float* __restrict__ Out, float* __restrict__ SinvG){
  __shared__ __attribute__((aligned(16))) char Kt[2][16384];
  __shared__ __attribute__((aligned(16))) char Vt[2][16384];
  __shared__ __attribute__((aligned(16))) char Et[8][4096];

  const int bid = blockIdx.x;              // 256 blocks
  const int xcd = bid & 7;                 // chunk bh per XCD for L2 locality
  const int loc = bid >> 3;                // 0..31
  const int bh  = xcd*4 + (loc & 3);
  const int p   = loc >> 2;                // 0..7
  const int t = threadIdx.x;
  const int lane = t & 63;
  const int w = t >> 6;
  const int s = w >> 2;                    // strip: 0=A, 1=B
  const int ws = w & 3;
  const int l15 = lane & 15, l4 = lane >> 4;
  const int swz = (l15 & 7) << 4;

  const int qt   = s ? p : (15 - p);
  const int q0   = qt * 128;
  const int nktA = 2*(15 - p) + 2;
  const int nktB = 2*p + 2;
  const int myNkt = s ? nktB : nktA;
  const int rbase = q0 + 32*ws;            // wave's first q-row

  // Q B-fragments for the wave's 2 row-groups (lane l15 = q within group)
  bf16x8 qa[2][4];
  #pragma unroll
  for (int g=0; g<2; ++g){
    const float* qb = Q + ((long)(bh*SQ) + rbase + 16*g + l15)*DD + 8*l4;
    #pragma unroll
    for (int kk=0;kk<4;kk++){
      float4 a = *(const float4*)(qb + 32*kk);
      float4 b = *(const float4*)(qb + 32*kk + 4);
      bf16x8 r;
      r[0]=(short)f2bf(a.x); r[1]=(short)f2bf(a.y); r[2]=(short)f2bf(a.z); r[3]=(short)f2bf(a.w);
      r[4]=(short)f2bf(b.x); r[5]=(short)f2bf(b.y); r[6]=(short)f2bf(b.z); r[7]=(short)f2bf(b.w);
      qa[g][kk]=r;
    }
  }

  const char* Kb = dqK + (long)bh*SQ*256;
  const char* Vb = dqVt + (long)bh*DD*4096;

  const f32x4 z4 = {0.f,0.f,0.f,0.f};
  f32x4 oacc[2][8] = {{z4,z4,z4,z4,z4,z4,z4,z4},{z4,z4,z4,z4,z4,z4,z4,z4}};
  float ssum[2] = {0.f, 0.f};
  char* eb = &Et[w][0];

  auto stage = [&](int buf, int kt){
    const char* ks = Kb + (long)kt*16384;
    gl_lds16(ks + t*16,        &Kt[buf][t*16]);
    gl_lds16(ks + 8192 + t*16, &Kt[buf][8192 + t*16]);
    const char* vs = Vb + (long)kt*128;
    gl_lds16(vs + (long)(t>>3)*4096      + (t&7)*16, &Vt[buf][t*16]);
    gl_lds16(vs + (long)(64+(t>>3))*4096 + (t&7)*16, &Vt[buf][8192 + t*16]);
  };

  stage(0, 0);
  __syncthreads();
  int cur = 0;
  for (int kt=0; kt<nktA; ++kt){
    if (kt+1 < nktA) stage(cur^1, kt+1);

    if (kt < myNkt){
      // --- QK^T swapped for both row-groups; K-frags read once ---
      f32x4 sacc[2][4] = {{z4,z4,z4,z4},{z4,z4,z4,z4}};
      {
        const char* kbase = &Kt[cur][0] + l15*256;
        __builtin_amdgcn_s_setprio(1);
        #pragma unroll
        for (int cf=0;cf<4;cf++){
          #pragma unroll
          for (int kk=0;kk<4;kk++){
            bf16x8 kb = *(const bf16x8*)(kbase + cf*4096 + ((64*kk+16*l4) ^ swz));
            sacc[0][cf] = __builtin_amdgcn_mfma_f32_16x16x32_bf16(kb, qa[0][kk], sacc[0][cf], 0,0,0);
            sacc[1][cf] = __builtin_amdgcn_mfma_f32_16x16x32_bf16(kb, qa[1][kk], sacc[1][cf], 0,0,0);
          }
        }
        __builtin_amdgcn_s_setprio(0);
      }

      // --- exp (+mask on the strip's 2 boundary tiles) -> Et ---
      const int k0 = kt*64;
      if (kt < 2*qt){
        #pragma unroll
        for (int g=0; g<2; ++g){
          const int lr = 16*g + l15;
          #pragma unroll
          for (int cf=0;cf<4;cf++){
            float e0 = exp2f(sacc[g][cf][0]*SC2);
            float e1 = exp2f(sacc[g][cf][1]*SC2);
            float e2 = exp2f(sacc[g][cf][2]*SC2);
            float e3 = exp2f(sacc[g][cf][3]*SC2);
            ssum[g] += (e0+e1) + (e2+e3);
            uint2 wp; wp.x = pack2bf(e0,e1); wp.y = pack2bf(e2,e3);
            *(uint2*)(eb + lr*128 + ((32*cf + 8*l4) ^ swz)) = wp;
          }
        }
      } else {
        #pragma unroll
        for (int g=0; g<2; ++g){
          const int lr = 16*g + l15;
          const int qrow = rbase + lr;
          #pragma unroll
          for (int cf=0;cf<4;cf++){
            const int tok0 = k0 + 16*cf + 4*l4;
            float e0 = (tok0+0 <= qrow) ? exp2f(sacc[g][cf][0]*SC2) : 0.f;
            float e1 = (tok0+1 <= qrow) ? exp2f(sacc[g][cf][1]*SC2) : 0.f;
            float e2 = (tok0+2 <= qrow) ? exp2f(sacc[g][cf][2]*SC2) : 0.f;
            float e3 = (tok0+3 <= qrow) ? exp2f(sacc[g][cf][3]*SC2) : 0.f;
            ssum[g] += (e0+e1) + (e2+e3);
            uint2 wp; wp.x = pack2bf(e0,e1); wp.y = pack2bf(e2,e3);
            *(uint2*)(eb + lr*128 + ((32*cf + 8*l4) ^ swz)) = wp;
          }
        }
      }

      // --- PV for both row-groups; V-frags read once ---
      {
        const char* vbase = &Vt[cur][0] + l15*128;
        __builtin_amdgcn_s_setprio(1);
        #pragma unroll
        for (int kc=0;kc<2;kc++){
          const int eo = (64*kc + 16*l4) ^ swz;
          bf16x8 ea0 = *(const bf16x8*)(eb + l15*128 + eo);
          bf16x8 ea1 = *(const bf16x8*)(eb + (16+l15)*128 + eo);
          #pragma unroll
          for (int df=0;df<8;df++){
            bf16x8 vv = *(const bf16x8*)(vbase + df*2048 + eo);
            oacc[0][df] = __builtin_amdgcn_mfma_f32_16x16x32_bf16(ea0, vv, oacc[0][df], 0,0,0);
            oacc[1][df] = __builtin_amdgcn_mfma_f32_16x16x32_bf16(ea1, vv, oacc[1][df], 0,0,0);
          }
        }
        __builtin_amdgcn_s_setprio(0);
      }
    }
    __syncthreads();   // buffer rotation + stage drain
    cur ^= 1;
  }

  // row sums + O write, per row-group
  #pragma unroll
  for (int g=0; g<2; ++g){
    float sm = ssum[g];
    sm += __shfl_xor(sm, 16);
    sm += __shfl_xor(sm, 32);
    const float sinv = 1.0f / sm;
    if (l4 == 0) SinvG[(long)bh*SQ + rbase + 16*g + l15] = sinv;
    float invr[4];
    #pragma unroll
    for (int i=0;i<4;i++) invr[i] = __shfl(sinv, 4*l4+i);
    float* ob = Out + ((long)(bh*SQ) + rbase + 16*g)*DD;
    #pragma unroll
    for (int df=0;df<8;df++){
      #pragma unroll
      for (int i=0;i<4;i++)
        ob[(4*l4+i)*DD + 16*df + l15] = oacc[g][df][i]*invr[i];
    }
  }
}

// ---------------------------------------------------------------------------
// Pass 2 (verified R3): weights = exp(S)/l (recompute QK^T), write-bound.
// Block = (bh, 64 q-rows), 4 waves; K staged LDS double-buffered.
// ---------------------------------------------------------------------------
__global__ __launch_bounds__(256) void attn2_kernel(const float* __restrict__ Q,
    const char* __restrict__ dqK, const float* __restrict__ SinvG,
    float* __restrict__ Wout){
  __shared__ __attribute__((aligned(16))) char Kt[2][16384];

  const int bid = blockIdx.x;
  const int xcd = bid & 7;
  const int loc = bid >> 3;           // 0..127
  const int bh  = xcd*4 + (loc >> 5);
  const int qt  = loc & 31;
  const int q0  = qt * 64;
  const int t = threadIdx.x;
  const int lane = t & 63;
  const int w = t >> 6;
  const int l15 = lane & 15, l4 = lane >> 4;
  const int swz = (l15 & 7) << 4;
  const int qrow = q0 + 16*w + l15;

  bf16x8 qa[4];
  {
    const float* qb = Q + ((long)(bh*SQ) + qrow)*DD + 8*l4;
    #pragma unroll
    for (int kk=0;kk<4;kk++){
      float4 a = *(const float4*)(qb + 32*kk);
      float4 b = *(const float4*)(qb + 32*kk + 4);
      bf16x8 r;
      r[0]=(short)f2bf(a.x); r[1]=(short)f2bf(a.y); r[2]=(short)f2bf(a.z); r[3]=(short)f2bf(a.w);
      r[4]=(short)f2bf(b.x); r[5]=(short)f2bf(b.y); r[6]=(short)f2bf(b.z); r[7]=(short)f2bf(b.w);
      qa[kk]=r;
    }
  }
  const float si = SinvG[(long)bh*SQ + qrow];
  const char* Kb = dqK + (long)bh*SQ*256;
  const int nkt = qt + 1;
  float* Wbase = Wout + (long)bh*SQ*SQ;
  float* wrow  = Wbase + (long)qrow*SQ;

  auto stage = [&](int buf, int kt){
    const char* ks = Kb + (long)kt*16384;
    #pragma unroll
    for (int i=0;i<4;i++)
      gl_lds16(ks + i*4096 + t*16, &Kt[buf][i*4096 + t*16]);
  };

  stage(0,0);
  __syncthreads();
  int cur = 0;
  const f32x4 z4 = {0.f,0.f,0.f,0.f};
  for (int kt=0; kt<nkt; ++kt){
    if (kt+1 < nkt) stage(cur^1, kt+1);
    const int k0 = kt*64;

    f32x4 sacc[4] = {z4,z4,z4,z4};
    {
      const char* kbase = &Kt[cur][0] + l15*256;
      __builtin_amdgcn_s_setprio(1);
      #pragma unroll
      for (int cf=0;cf<4;cf++){
        #pragma unroll
        for (int kk=0;kk<4;kk++){
          bf16x8 kb = *(const bf16x8*)(kbase + cf*4096 + ((64*kk+16*l4) ^ swz));
          sacc[cf] = __builtin_amdgcn_mfma_f32_16x16x32_bf16(kb, qa[kk], sacc[cf], 0,0,0);
        }
      }
      __builtin_amdgcn_s_setprio(0);
    }

    if (kt < qt){   // full tile
      #pragma unroll
      for (int cf=0;cf<4;cf++){
        const int tok0 = k0 + 16*cf + 4*l4;
        float4 wv;
        wv.x = exp2f(sacc[cf][0]*SC2)*si;
        wv.y = exp2f(sacc[cf][1]*SC2)*si;
        wv.z = exp2f(sacc[cf][2]*SC2)*si;
        wv.w = exp2f(sacc[cf][3]*SC2)*si;
        *(float4*)(wrow + tok0) = wv;
      }
    } else {        // diagonal tile
      #pragma unroll
      for (int cf=0;cf<4;cf++){
        const int tok0 = k0 + 16*cf + 4*l4;
        float4 wv;
        wv.x = (tok0+0 <= qrow) ? exp2f(sacc[cf][0]*SC2)*si : 0.f;
        wv.y = (tok0+1 <= qrow) ? exp2f(sacc[cf][1]*SC2)*si : 0.f;
        wv.z = (tok0+2 <= qrow) ? exp2f(sacc[cf][2]*SC2)*si : 0.f;
        wv.w = (tok0+3 <= qrow) ? exp2f(sacc[cf][3]*SC2)*si : 0.f;
        *(float4*)(wrow + tok0) = wv;
      }
    }
    __syncthreads();
    cur ^= 1;
  }

  // zero-fill fully-masked columns [nkt*64, 2048)
  const int z0 = nkt*64;
  if (z0 < SQ){
    float* wr = Wbase + (long)(q0 + 16*w)*SQ;
    const float4 zz = {0.f,0.f,0.f,0.f};
    for (int r=0;r<16;r++){
      float* row = wr + (long)r*SQ;
      for (int c = z0 + 4*lane; c < SQ; c += 256)
        *(float4*)(row + c) = zz;
    }
  }
}

extern "C" void kernel_launch(void* const* d_in, const int* in_sizes, int n_in,
                              void* d_out, int out_size, void* d_ws, size_t ws_size,
                              hipStream_t stream) {
  const float* Q = (const float*)d_in[0];
  const float* K = (const float*)d_in[1];
  const float* V = (const float*)d_in[2];
  float* Out = (float*)d_out;
  float* Wout = (float*)d_out + (size_t)BHN*SQ*DD;
  char* dqK  = (char*)d_ws;                                // 16 MB
  char* dqVt = (char*)d_ws + (size_t)BHN*SQ*DD*2;          // 16 MB
  float* SinvG = (float*)((char*)d_ws + (size_t)BHN*SQ*DD*4);  // 256 KB @ +32MB

  qd_kernel<<<BHN*32, 256, 0, stream>>>(K, V, dqK, dqVt);
  attn1_kernel<<<256, 512, 0, stream>>>(Q, dqK, dqVt, Out, SinvG);
  attn2_kernel<<<1024, 256, 0, stream>>>(Q, dqK, SinvG, Wout);
}

// Round 5
// 272.468 us; speedup vs baseline: 1.5804x; 1.0310x over previous
//
#include <hip/hip_runtime.h>

#define SQ 2048
#define DD 128
#define BHN 32                          // B*H = 2*16
// exp(s/sqrt(128)) == exp2(s * SC2)
#define SC2 0.12751741934f

typedef __attribute__((ext_vector_type(8))) short bf16x8;
typedef __attribute__((ext_vector_type(4))) float f32x4;

// f32 -> bf16 round-to-nearest-even
__device__ __forceinline__ unsigned short f2bf(float x){
  unsigned int u = __float_as_uint(x);
  unsigned int r = (u + 0x7FFFu + ((u >> 16) & 1u)) >> 16;
  return (unsigned short)r;
}
__device__ __forceinline__ unsigned pack2bf(float a, float b){
  return (unsigned)f2bf(a) | ((unsigned)f2bf(b) << 16);
}

// async 16B global->LDS (dest = wave-uniform base + lane*16, linear)
__device__ __forceinline__ void gl_lds16(const void* g, void* l){
  __builtin_amdgcn_global_load_lds(
      (const __attribute__((address_space(1))) unsigned int*)g,
      (__attribute__((address_space(3))) unsigned int*)l, 16, 0, 0);
}

// ---------------------------------------------------------------------------
// Kernel 1 (verified R1-R4): quant-dequant K (per-token) and V (grouped-64).
// dqK:  [bh][s][d] rows of 256B, bytes within row XOR-swizzled by (s&7)<<4.
// dqVt: [bh][d][s] rows of 4096B; within each aligned 128B block (64 tokens)
//       bytes XOR-swizzled by (d&7)<<4.
// ---------------------------------------------------------------------------
__global__ __launch_bounds__(256) void qd_kernel(const float* __restrict__ K,
                                                 const float* __restrict__ V,
                                                 char* __restrict__ dqK,
                                                 char* __restrict__ dqVt){
  __shared__ float Vlds[128*65];
  const int t = threadIdx.x;
  const int bh = blockIdx.x >> 5;
  const int stile = blockIdx.x & 31;
  const int tt = t >> 2;
  const int q4 = t & 3;
  const int s = stile*64 + tt;
  const long ebase = ((long)(bh*SQ + s))*DD + 32*q4;

  float vals[32];
  {
    const float4* kp = (const float4*)(K + ebase);
    float am = 0.f;
    #pragma unroll
    for (int j=0;j<8;j++){
      float4 v4 = kp[j];
      vals[4*j+0]=v4.x; vals[4*j+1]=v4.y; vals[4*j+2]=v4.z; vals[4*j+3]=v4.w;
      am = fmaxf(am, fmaxf(fmaxf(fabsf(v4.x),fabsf(v4.y)),fmaxf(fabsf(v4.z),fabsf(v4.w))));
    }
    am = fmaxf(am, __shfl_xor(am,1));
    am = fmaxf(am, __shfl_xor(am,2));
    const float sc = fmaxf(am/7.0f, 1e-8f);
    #pragma unroll
    for (int j=0;j<32;j++){
      float qv = rintf(vals[j]/sc);
      qv = fminf(7.f, fmaxf(-7.f, qv));
      vals[j] = qv*sc;
    }
    const long rowb = ((long)(bh*SQ + s))*256;
    const int swz = (s & 7) << 4;
    #pragma unroll
    for (int c=0;c<4;c++){
      uint4 w;
      w.x = pack2bf(vals[8*c+0], vals[8*c+1]);
      w.y = pack2bf(vals[8*c+2], vals[8*c+3]);
      w.z = pack2bf(vals[8*c+4], vals[8*c+5]);
      w.w = pack2bf(vals[8*c+6], vals[8*c+7]);
      *(uint4*)(dqK + rowb + ((64*q4 + 16*c) ^ swz)) = w;
    }
  }
  {
    const float4* vp = (const float4*)(V + ebase);
    float am = 0.f;
    #pragma unroll
    for (int j=0;j<8;j++){
      float4 v4 = vp[j];
      vals[4*j+0]=v4.x; vals[4*j+1]=v4.y; vals[4*j+2]=v4.z; vals[4*j+3]=v4.w;
      am = fmaxf(am, fmaxf(fmaxf(fabsf(v4.x),fabsf(v4.y)),fmaxf(fabsf(v4.z),fabsf(v4.w))));
    }
    am = fmaxf(am, __shfl_xor(am,1));
    const float sc = fmaxf(am/7.0f, 1e-8f);
    #pragma unroll
    for (int j=0;j<32;j++){
      float qv = rintf(vals[j]/sc);
      qv = fminf(7.f, fmaxf(-7.f, qv));
      Vlds[(32*q4 + j)*65 + tt] = qv*sc;
    }
  }
  __syncthreads();
  #pragma unroll
  for (int m=0;m<4;m++){
    const int chunk = m*256 + t;
    const int d = chunk >> 3;
    const int c = chunk & 7;
    uint4 w;
    const float* f = &Vlds[d*65 + 8*c];
    w.x = pack2bf(f[0], f[1]);
    w.y = pack2bf(f[2], f[3]);
    w.z = pack2bf(f[4], f[5]);
    w.w = pack2bf(f[6], f[7]);
    const long ob = ((long)(bh*DD + d))*4096 + (long)stile*128 + ((16*c) ^ ((d&7)<<4));
    *(uint4*)(dqVt + ob) = w;
  }
}

// ---------------------------------------------------------------------------
// Pass 1: O + row-sums. 512 blocks (2/CU), 4 waves, 80KB LDS.
// Waves 0-1: strip A (qt=31-p, 64 rows), waves 2-3: strip B (qt=p).
// Joint k-loop over nktA tiles; B-waves compute only while kt<nktB; every
// block does nktA+nktB = 33 compute-units -> uniform work.
// Each wave owns 32 q-rows (2 MFMA row-groups) -> K/V LDS reads amortized 2x.
// Co-resident blocks (bid, bid+256) share bh -> L2 reuse; 2 blocks/CU so
// one block's compute covers the other's barrier/stage drains.
// ---------------------------------------------------------------------------
__global__ __launch_bounds__(256,2) void attn1_kernel(const float* __restrict__ Q,
    const char* __restrict__ dqK, const char* __restrict__ dqVt,
    float* __restrict__ Out, float* __restrict__ SinvG){
  __shared__ __attribute__((aligned(16))) char Kt[2][16384];
  __shared__ __attribute__((aligned(16))) char Vt[2][16384];
  __shared__ __attribute__((aligned(16))) char Et[4][4096];

  const int bid = blockIdx.x;              // 512 blocks
  const int xcd = bid & 7;                 // chunk bh per XCD for L2 locality
  const int loc = bid >> 3;                // 0..63
  const int bh  = xcd*4 + (loc & 3);
  const int p   = loc >> 2;                // 0..15
  const int t = threadIdx.x;
  const int lane = t & 63;
  const int w = t >> 6;                    // 0..3
  const int s = w >> 1;                    // strip: 0=A, 1=B
  const int ws = w & 1;
  const int l15 = lane & 15, l4 = lane >> 4;
  const int swz = (l15 & 7) << 4;

  const int qt   = s ? p : (31 - p);
  const int q0   = qt * 64;
  const int nktA = 32 - p;
  const int myNkt = qt + 1;
  const int rbase = q0 + 32*ws;            // wave's first q-row

  // Q B-fragments for the wave's 2 row-groups (lane l15 = q within group)
  bf16x8 qa[2][4];
  #pragma unroll
  for (int g=0; g<2; ++g){
    const float* qb = Q + ((long)(bh*SQ) + rbase + 16*g + l15)*DD + 8*l4;
    #pragma unroll
    for (int kk=0;kk<4;kk++){
      float4 a = *(const float4*)(qb + 32*kk);
      float4 b = *(const float4*)(qb + 32*kk + 4);
      bf16x8 r;
      r[0]=(short)f2bf(a.x); r[1]=(short)f2bf(a.y); r[2]=(short)f2bf(a.z); r[3]=(short)f2bf(a.w);
      r[4]=(short)f2bf(b.x); r[5]=(short)f2bf(b.y); r[6]=(short)f2bf(b.z); r[7]=(short)f2bf(b.w);
      qa[g][kk]=r;
    }
  }

  const char* Kb = dqK + (long)bh*SQ*256;
  const char* Vb = dqVt + (long)bh*DD*4096;

  const f32x4 z4 = {0.f,0.f,0.f,0.f};
  f32x4 oacc[2][8] = {{z4,z4,z4,z4,z4,z4,z4,z4},{z4,z4,z4,z4,z4,z4,z4,z4}};
  float ssum[2] = {0.f, 0.f};
  char* eb = &Et[w][0];

  auto stage = [&](int buf, int kt){
    const char* ks = Kb + (long)kt*16384;
    #pragma unroll
    for (int i=0;i<4;i++)
      gl_lds16(ks + i*4096 + t*16, &Kt[buf][i*4096 + t*16]);
    const char* vs = Vb + (long)kt*128;
    #pragma unroll
    for (int i=0;i<4;i++)
      gl_lds16(vs + (long)(i*32 + (t>>3))*4096 + (t&7)*16, &Vt[buf][i*4096 + t*16]);
  };

  stage(0, 0);
  __syncthreads();
  int cur = 0;
  for (int kt=0; kt<nktA; ++kt){
    if (kt+1 < nktA) stage(cur^1, kt+1);

    if (kt < myNkt){
      // --- QK^T swapped for both row-groups; K-frags read once ---
      f32x4 sacc[2][4] = {{z4,z4,z4,z4},{z4,z4,z4,z4}};
      {
        const char* kbase = &Kt[cur][0] + l15*256;
        __builtin_amdgcn_s_setprio(1);
        #pragma unroll
        for (int cf=0;cf<4;cf++){
          #pragma unroll
          for (int kk=0;kk<4;kk++){
            bf16x8 kb = *(const bf16x8*)(kbase + cf*4096 + ((64*kk+16*l4) ^ swz));
            sacc[0][cf] = __builtin_amdgcn_mfma_f32_16x16x32_bf16(kb, qa[0][kk], sacc[0][cf], 0,0,0);
            sacc[1][cf] = __builtin_amdgcn_mfma_f32_16x16x32_bf16(kb, qa[1][kk], sacc[1][cf], 0,0,0);
          }
        }
        __builtin_amdgcn_s_setprio(0);
      }

      // --- exp (+mask on the strip's diagonal tile) -> Et ---
      const int k0 = kt*64;
      if (kt < qt){
        #pragma unroll
        for (int g=0; g<2; ++g){
          const int lr = 16*g + l15;
          #pragma unroll
          for (int cf=0;cf<4;cf++){
            float e0 = exp2f(sacc[g][cf][0]*SC2);
            float e1 = exp2f(sacc[g][cf][1]*SC2);
            float e2 = exp2f(sacc[g][cf][2]*SC2);
            float e3 = exp2f(sacc[g][cf][3]*SC2);
            ssum[g] += (e0+e1) + (e2+e3);
            uint2 wp; wp.x = pack2bf(e0,e1); wp.y = pack2bf(e2,e3);
            *(uint2*)(eb + lr*128 + ((32*cf + 8*l4) ^ swz)) = wp;
          }
        }
      } else {
        #pragma unroll
        for (int g=0; g<2; ++g){
          const int lr = 16*g + l15;
          const int qrow = rbase + lr;
          #pragma unroll
          for (int cf=0;cf<4;cf++){
            const int tok0 = k0 + 16*cf + 4*l4;
            float e0 = (tok0+0 <= qrow) ? exp2f(sacc[g][cf][0]*SC2) : 0.f;
            float e1 = (tok0+1 <= qrow) ? exp2f(sacc[g][cf][1]*SC2) : 0.f;
            float e2 = (tok0+2 <= qrow) ? exp2f(sacc[g][cf][2]*SC2) : 0.f;
            float e3 = (tok0+3 <= qrow) ? exp2f(sacc[g][cf][3]*SC2) : 0.f;
            ssum[g] += (e0+e1) + (e2+e3);
            uint2 wp; wp.x = pack2bf(e0,e1); wp.y = pack2bf(e2,e3);
            *(uint2*)(eb + lr*128 + ((32*cf + 8*l4) ^ swz)) = wp;
          }
        }
      }

      // --- PV for both row-groups; V-frags read once ---
      {
        const char* vbase = &Vt[cur][0] + l15*128;
        __builtin_amdgcn_s_setprio(1);
        #pragma unroll
        for (int kc=0;kc<2;kc++){
          const int eo = (64*kc + 16*l4) ^ swz;
          bf16x8 ea0 = *(const bf16x8*)(eb + l15*128 + eo);
          bf16x8 ea1 = *(const bf16x8*)(eb + (16+l15)*128 + eo);
          #pragma unroll
          for (int df=0;df<8;df++){
            bf16x8 vv = *(const bf16x8*)(vbase + df*2048 + eo);
            oacc[0][df] = __builtin_amdgcn_mfma_f32_16x16x32_bf16(ea0, vv, oacc[0][df], 0,0,0);
            oacc[1][df] = __builtin_amdgcn_mfma_f32_16x16x32_bf16(ea1, vv, oacc[1][df], 0,0,0);
          }
        }
        __builtin_amdgcn_s_setprio(0);
      }
    }
    __syncthreads();   // buffer rotation + stage drain
    cur ^= 1;
  }

  // row sums + O write, per row-group
  #pragma unroll
  for (int g=0; g<2; ++g){
    float sm = ssum[g];
    sm += __shfl_xor(sm, 16);
    sm += __shfl_xor(sm, 32);
    const float sinv = 1.0f / sm;
    if (l4 == 0) SinvG[(long)bh*SQ + rbase + 16*g + l15] = sinv;
    float invr[4];
    #pragma unroll
    for (int i=0;i<4;i++) invr[i] = __shfl(sinv, 4*l4+i);
    float* ob = Out + ((long)(bh*SQ) + rbase + 16*g)*DD;
    #pragma unroll
    for (int df=0;df<8;df++){
      #pragma unroll
      for (int i=0;i<4;i++)
        ob[(4*l4+i)*DD + 16*df + l15] = oacc[g][df][i]*invr[i];
    }
  }
}

// ---------------------------------------------------------------------------
// Pass 2: weights = exp(S)/l (recompute QK^T), write-bound.
// Block = (bh, 64 q-rows), 4 waves; K staged LDS double-buffered.
// bid = xcd + 8*(bh&3) + 32*qt: co-resident CU blocks get qt,qt+8,qt+16,qt+24
// (balanced compute) while all blocks of a bh stay on one XCD (L2 reuse).
// ---------------------------------------------------------------------------
__global__ __launch_bounds__(256) void attn2_kernel(const float* __restrict__ Q,
    const char* __restrict__ dqK, const float* __restrict__ SinvG,
    float* __restrict__ Wout){
  __shared__ __attribute__((aligned(16))) char Kt[2][16384];

  const int bid = blockIdx.x;
  const int qt  = bid >> 5;           // 0..31
  const int r   = bid & 31;
  const int bh  = 4*(r & 7) + (r >> 3);
  const int q0  = qt * 64;
  const int t = threadIdx.x;
  const int lane = t & 63;
  const int w = t >> 6;
  const int l15 = lane & 15, l4 = lane >> 4;
  const int swz = (l15 & 7) << 4;
  const int qrow = q0 + 16*w + l15;

  bf16x8 qa[4];
  {
    const float* qb = Q + ((long)(bh*SQ) + qrow)*DD + 8*l4;
    #pragma unroll
    for (int kk=0;kk<4;kk++){
      float4 a = *(const float4*)(qb + 32*kk);
      float4 b = *(const float4*)(qb + 32*kk + 4);
      bf16x8 r2;
      r2[0]=(short)f2bf(a.x); r2[1]=(short)f2bf(a.y); r2[2]=(short)f2bf(a.z); r2[3]=(short)f2bf(a.w);
      r2[4]=(short)f2bf(b.x); r2[5]=(short)f2bf(b.y); r2[6]=(short)f2bf(b.z); r2[7]=(short)f2bf(b.w);
      qa[kk]=r2;
    }
  }
  const float si = SinvG[(long)bh*SQ + qrow];
  const char* Kb = dqK + (long)bh*SQ*256;
  const int nkt = qt + 1;
  float* Wbase = Wout + (long)bh*SQ*SQ;
  float* wrow  = Wbase + (long)qrow*SQ;

  auto stage = [&](int buf, int kt){
    const char* ks = Kb + (long)kt*16384;
    #pragma unroll
    for (int i=0;i<4;i++)
      gl_lds16(ks + i*4096 + t*16, &Kt[buf][i*4096 + t*16]);
  };

  stage(0,0);
  __syncthreads();
  int cur = 0;
  const f32x4 z4 = {0.f,0.f,0.f,0.f};
  for (int kt=0; kt<nkt; ++kt){
    if (kt+1 < nkt) stage(cur^1, kt+1);
    const int k0 = kt*64;

    f32x4 sacc[4] = {z4,z4,z4,z4};
    {
      const char* kbase = &Kt[cur][0] + l15*256;
      __builtin_amdgcn_s_setprio(1);
      #pragma unroll
      for (int cf=0;cf<4;cf++){
        #pragma unroll
        for (int kk=0;kk<4;kk++){
          bf16x8 kb = *(const bf16x8*)(kbase + cf*4096 + ((64*kk+16*l4) ^ swz));
          sacc[cf] = __builtin_amdgcn_mfma_f32_16x16x32_bf16(kb, qa[kk], sacc[cf], 0,0,0);
        }
      }
      __builtin_amdgcn_s_setprio(0);
    }

    if (kt < qt){   // full tile
      #pragma unroll
      for (int cf=0;cf<4;cf++){
        const int tok0 = k0 + 16*cf + 4*l4;
        float4 wv;
        wv.x = exp2f(sacc[cf][0]*SC2)*si;
        wv.y = exp2f(sacc[cf][1]*SC2)*si;
        wv.z = exp2f(sacc[cf][2]*SC2)*si;
        wv.w = exp2f(sacc[cf][3]*SC2)*si;
        *(float4*)(wrow + tok0) = wv;
      }
    } else {        // diagonal tile
      #pragma unroll
      for (int cf=0;cf<4;cf++){
        const int tok0 = k0 + 16*cf + 4*l4;
        float4 wv;
        wv.x = (tok0+0 <= qrow) ? exp2f(sacc[cf][0]*SC2)*si : 0.f;
        wv.y = (tok0+1 <= qrow) ? exp2f(sacc[cf][1]*SC2)*si : 0.f;
        wv.z = (tok0+2 <= qrow) ? exp2f(sacc[cf][2]*SC2)*si : 0.f;
        wv.w = (tok0+3 <= qrow) ? exp2f(sacc[cf][3]*SC2)*si : 0.f;
        *(float4*)(wrow + tok0) = wv;
      }
    }
    __syncthreads();
    cur ^= 1;
  }

  // zero-fill fully-masked columns [nkt*64, 2048)
  const int z0 = nkt*64;
  if (z0 < SQ){
    float* wr = Wbase + (long)(q0 + 16*w)*SQ;
    const float4 zz = {0.f,0.f,0.f,0.f};
    for (int rr=0;rr<16;rr++){
      float* row = wr + (long)rr*SQ;
      for (int c = z0 + 4*lane; c < SQ; c += 256)
        *(float4*)(row + c) = zz;
    }
  }
}

extern "C" void kernel_launch(void* const* d_in, const int* in_sizes, int n_in,
                              void* d_out, int out_size, void* d_ws, size_t ws_size,
                              hipStream_t stream) {
  const float* Q = (const float*)d_in[0];
  const float* K = (const float*)d_in[1];
  const float* V = (const float*)d_in[2];
  float* Out = (float*)d_out;
  float* Wout = (float*)d_out + (size_t)BHN*SQ*DD;
  char* dqK  = (char*)d_ws;                                // 16 MB
  char* dqVt = (char*)d_ws + (size_t)BHN*SQ*DD*2;          // 16 MB
  float* SinvG = (float*)((char*)d_ws + (size_t)BHN*SQ*DD*4);  // 256 KB @ +32MB

  qd_kernel<<<BHN*32, 256, 0, stream>>>(K, V, dqK, dqVt);
  attn1_kernel<<<512, 256, 0, stream>>>(Q, dqK, dqVt, Out, SinvG);
  attn2_kernel<<<1024, 256, 0, stream>>>(Q, dqK, SinvG, Wout);
}

// Round 6
// 242.301 us; speedup vs baseline: 1.7771x; 1.1245x over previous
//
#include <hip/hip_runtime.h>

#define SQ 2048
#define DD 128
#define BHN 32                          // B*H = 2*16
// exp(s/sqrt(128)) == exp2(s * SC2)
#define SC2 0.12751741934f

typedef __attribute__((ext_vector_type(8))) short bf16x8;
typedef __attribute__((ext_vector_type(4))) float f32x4;

// f32 -> bf16 round-to-nearest-even
__device__ __forceinline__ unsigned short f2bf(float x){
  unsigned int u = __float_as_uint(x);
  unsigned int r = (u + 0x7FFFu + ((u >> 16) & 1u)) >> 16;
  return (unsigned short)r;
}
__device__ __forceinline__ unsigned pack2bf(float a, float b){
  return (unsigned)f2bf(a) | ((unsigned)f2bf(b) << 16);
}

// async 16B global->LDS (dest = wave-uniform base + lane*16, linear)
__device__ __forceinline__ void gl_lds16(const void* g, void* l){
  __builtin_amdgcn_global_load_lds(
      (const __attribute__((address_space(1))) unsigned int*)g,
      (__attribute__((address_space(3))) unsigned int*)l, 16, 0, 0);
}

// ---------------------------------------------------------------------------
// Kernel 1 (verified R1-R5): quant-dequant K (per-token) and V (grouped-64).
// dqK:  [bh][s][d] rows of 256B, bytes within row XOR-swizzled by (s&7)<<4.
// dqVt: [bh][d][s] rows of 4096B; within each aligned 128B block (64 tokens)
//       bytes XOR-swizzled by (d&7)<<4.
// ---------------------------------------------------------------------------
__global__ __launch_bounds__(256) void qd_kernel(const float* __restrict__ K,
                                                 const float* __restrict__ V,
                                                 char* __restrict__ dqK,
                                                 char* __restrict__ dqVt){
  __shared__ float Vlds[128*65];
  const int t = threadIdx.x;
  const int bh = blockIdx.x >> 5;
  const int stile = blockIdx.x & 31;
  const int tt = t >> 2;
  const int q4 = t & 3;
  const int s = stile*64 + tt;
  const long ebase = ((long)(bh*SQ + s))*DD + 32*q4;

  float vals[32];
  {
    const float4* kp = (const float4*)(K + ebase);
    float am = 0.f;
    #pragma unroll
    for (int j=0;j<8;j++){
      float4 v4 = kp[j];
      vals[4*j+0]=v4.x; vals[4*j+1]=v4.y; vals[4*j+2]=v4.z; vals[4*j+3]=v4.w;
      am = fmaxf(am, fmaxf(fmaxf(fabsf(v4.x),fabsf(v4.y)),fmaxf(fabsf(v4.z),fabsf(v4.w))));
    }
    am = fmaxf(am, __shfl_xor(am,1));
    am = fmaxf(am, __shfl_xor(am,2));
    const float sc = fmaxf(am/7.0f, 1e-8f);
    #pragma unroll
    for (int j=0;j<32;j++){
      float qv = rintf(vals[j]/sc);
      qv = fminf(7.f, fmaxf(-7.f, qv));
      vals[j] = qv*sc;
    }
    const long rowb = ((long)(bh*SQ + s))*256;
    const int swz = (s & 7) << 4;
    #pragma unroll
    for (int c=0;c<4;c++){
      uint4 w;
      w.x = pack2bf(vals[8*c+0], vals[8*c+1]);
      w.y = pack2bf(vals[8*c+2], vals[8*c+3]);
      w.z = pack2bf(vals[8*c+4], vals[8*c+5]);
      w.w = pack2bf(vals[8*c+6], vals[8*c+7]);
      *(uint4*)(dqK + rowb + ((64*q4 + 16*c) ^ swz)) = w;
    }
  }
  {
    const float4* vp = (const float4*)(V + ebase);
    float am = 0.f;
    #pragma unroll
    for (int j=0;j<8;j++){
      float4 v4 = vp[j];
      vals[4*j+0]=v4.x; vals[4*j+1]=v4.y; vals[4*j+2]=v4.z; vals[4*j+3]=v4.w;
      am = fmaxf(am, fmaxf(fmaxf(fabsf(v4.x),fabsf(v4.y)),fmaxf(fabsf(v4.z),fabsf(v4.w))));
    }
    am = fmaxf(am, __shfl_xor(am,1));
    const float sc = fmaxf(am/7.0f, 1e-8f);
    #pragma unroll
    for (int j=0;j<32;j++){
      float qv = rintf(vals[j]/sc);
      qv = fminf(7.f, fmaxf(-7.f, qv));
      Vlds[(32*q4 + j)*65 + tt] = qv*sc;
    }
  }
  __syncthreads();
  #pragma unroll
  for (int m=0;m<4;m++){
    const int chunk = m*256 + t;
    const int d = chunk >> 3;
    const int c = chunk & 7;
    uint4 w;
    const float* f = &Vlds[d*65 + 8*c];
    w.x = pack2bf(f[0], f[1]);
    w.y = pack2bf(f[2], f[3]);
    w.z = pack2bf(f[4], f[5]);
    w.w = pack2bf(f[6], f[7]);
    const long ob = ((long)(bh*DD + d))*4096 + (long)stile*128 + ((16*c) ^ ((d&7)<<4));
    *(uint4*)(dqVt + ob) = w;
  }
}

// ---------------------------------------------------------------------------
// Fused attention: 512 blocks (2/CU), 4 waves, 80KB LDS.
// Waves 0-1: strip A (qt=31-p, 64 rows), waves 2-3: strip B (qt=p).
// PASS 1 (k-loop, nktA tiles): QK^T -> exp -> E(LDS) -> PV + rowsum; O write.
// PASS 2 (k-loop again, K-only staging): recompute QK^T, write weights/l,
// zero-fill masked region. sinv stays in registers. Uniform 66 tile-units.
// ---------------------------------------------------------------------------
__global__ __launch_bounds__(256,2) void attn_fused(const float* __restrict__ Q,
    const char* __restrict__ dqK, const char* __restrict__ dqVt,
    float* __restrict__ Out, float* __restrict__ Wout){
  __shared__ __attribute__((aligned(16))) char Kt[2][16384];
  __shared__ __attribute__((aligned(16))) char Vt[2][16384];
  __shared__ __attribute__((aligned(16))) char Et[4][4096];

  const int bid = blockIdx.x;              // 512 blocks
  const int xcd = bid & 7;                 // chunk bh per XCD for L2 locality
  const int loc = bid >> 3;                // 0..63
  const int bh  = xcd*4 + (loc & 3);
  const int p   = loc >> 2;                // 0..15
  const int t = threadIdx.x;
  const int lane = t & 63;
  const int w = t >> 6;                    // 0..3
  const int s = w >> 1;                    // strip: 0=A, 1=B
  const int ws = w & 1;
  const int l15 = lane & 15, l4 = lane >> 4;
  const int swz = (l15 & 7) << 4;

  const int qt   = s ? p : (31 - p);
  const int q0   = qt * 64;
  const int nktA = 32 - p;
  const int myNkt = qt + 1;
  const int rbase = q0 + 32*ws;            // wave's first q-row

  // Q B-fragments for the wave's 2 row-groups (lane l15 = q within group)
  bf16x8 qa[2][4];
  #pragma unroll
  for (int g=0; g<2; ++g){
    const float* qb = Q + ((long)(bh*SQ) + rbase + 16*g + l15)*DD + 8*l4;
    #pragma unroll
    for (int kk=0;kk<4;kk++){
      float4 a = *(const float4*)(qb + 32*kk);
      float4 b = *(const float4*)(qb + 32*kk + 4);
      bf16x8 r;
      r[0]=(short)f2bf(a.x); r[1]=(short)f2bf(a.y); r[2]=(short)f2bf(a.z); r[3]=(short)f2bf(a.w);
      r[4]=(short)f2bf(b.x); r[5]=(short)f2bf(b.y); r[6]=(short)f2bf(b.z); r[7]=(short)f2bf(b.w);
      qa[g][kk]=r;
    }
  }

  const char* Kb = dqK + (long)bh*SQ*256;
  const char* Vb = dqVt + (long)bh*DD*4096;

  const f32x4 z4 = {0.f,0.f,0.f,0.f};
  f32x4 oacc[2][8] = {{z4,z4,z4,z4,z4,z4,z4,z4},{z4,z4,z4,z4,z4,z4,z4,z4}};
  float ssum[2] = {0.f, 0.f};
  char* eb = &Et[w][0];

  auto stageKV = [&](int buf, int kt){
    const char* ks = Kb + (long)kt*16384;
    #pragma unroll
    for (int i=0;i<4;i++)
      gl_lds16(ks + i*4096 + t*16, &Kt[buf][i*4096 + t*16]);
    const char* vs = Vb + (long)kt*128;
    #pragma unroll
    for (int i=0;i<4;i++)
      gl_lds16(vs + (long)(i*32 + (t>>3))*4096 + (t&7)*16, &Vt[buf][i*4096 + t*16]);
  };
  auto stageK = [&](int buf, int kt){
    const char* ks = Kb + (long)kt*16384;
    #pragma unroll
    for (int i=0;i<4;i++)
      gl_lds16(ks + i*4096 + t*16, &Kt[buf][i*4096 + t*16]);
  };

  // ======================= PASS 1 =======================
  stageKV(0, 0);
  __syncthreads();
  int cur = 0;
  for (int kt=0; kt<nktA; ++kt){
    if (kt+1 < nktA) stageKV(cur^1, kt+1);

    if (kt < myNkt){
      // --- QK^T swapped for both row-groups; K-frags read once ---
      f32x4 sacc[2][4] = {{z4,z4,z4,z4},{z4,z4,z4,z4}};
      {
        const char* kbase = &Kt[cur][0] + l15*256;
        __builtin_amdgcn_s_setprio(1);
        #pragma unroll
        for (int cf=0;cf<4;cf++){
          #pragma unroll
          for (int kk=0;kk<4;kk++){
            bf16x8 kb = *(const bf16x8*)(kbase + cf*4096 + ((64*kk+16*l4) ^ swz));
            sacc[0][cf] = __builtin_amdgcn_mfma_f32_16x16x32_bf16(kb, qa[0][kk], sacc[0][cf], 0,0,0);
            sacc[1][cf] = __builtin_amdgcn_mfma_f32_16x16x32_bf16(kb, qa[1][kk], sacc[1][cf], 0,0,0);
          }
        }
        __builtin_amdgcn_s_setprio(0);
      }

      // --- exp (+mask on the strip's diagonal tile) -> Et ---
      const int k0 = kt*64;
      if (kt < qt){
        #pragma unroll
        for (int g=0; g<2; ++g){
          const int lr = 16*g + l15;
          #pragma unroll
          for (int cf=0;cf<4;cf++){
            float e0 = exp2f(sacc[g][cf][0]*SC2);
            float e1 = exp2f(sacc[g][cf][1]*SC2);
            float e2 = exp2f(sacc[g][cf][2]*SC2);
            float e3 = exp2f(sacc[g][cf][3]*SC2);
            ssum[g] += (e0+e1) + (e2+e3);
            uint2 wp; wp.x = pack2bf(e0,e1); wp.y = pack2bf(e2,e3);
            *(uint2*)(eb + lr*128 + ((32*cf + 8*l4) ^ swz)) = wp;
          }
        }
      } else {
        #pragma unroll
        for (int g=0; g<2; ++g){
          const int lr = 16*g + l15;
          const int qrow = rbase + lr;
          #pragma unroll
          for (int cf=0;cf<4;cf++){
            const int tok0 = k0 + 16*cf + 4*l4;
            float e0 = (tok0+0 <= qrow) ? exp2f(sacc[g][cf][0]*SC2) : 0.f;
            float e1 = (tok0+1 <= qrow) ? exp2f(sacc[g][cf][1]*SC2) : 0.f;
            float e2 = (tok0+2 <= qrow) ? exp2f(sacc[g][cf][2]*SC2) : 0.f;
            float e3 = (tok0+3 <= qrow) ? exp2f(sacc[g][cf][3]*SC2) : 0.f;
            ssum[g] += (e0+e1) + (e2+e3);
            uint2 wp; wp.x = pack2bf(e0,e1); wp.y = pack2bf(e2,e3);
            *(uint2*)(eb + lr*128 + ((32*cf + 8*l4) ^ swz)) = wp;
          }
        }
      }

      // --- PV for both row-groups; V-frags read once ---
      {
        const char* vbase = &Vt[cur][0] + l15*128;
        __builtin_amdgcn_s_setprio(1);
        #pragma unroll
        for (int kc=0;kc<2;kc++){
          const int eo = (64*kc + 16*l4) ^ swz;
          bf16x8 ea0 = *(const bf16x8*)(eb + l15*128 + eo);
          bf16x8 ea1 = *(const bf16x8*)(eb + (16+l15)*128 + eo);
          #pragma unroll
          for (int df=0;df<8;df++){
            bf16x8 vv = *(const bf16x8*)(vbase + df*2048 + eo);
            oacc[0][df] = __builtin_amdgcn_mfma_f32_16x16x32_bf16(ea0, vv, oacc[0][df], 0,0,0);
            oacc[1][df] = __builtin_amdgcn_mfma_f32_16x16x32_bf16(ea1, vv, oacc[1][df], 0,0,0);
          }
        }
        __builtin_amdgcn_s_setprio(0);
      }
    }
    __syncthreads();   // buffer rotation + stage drain
    cur ^= 1;
  }

  // row sums + O write; sinv kept in registers for pass 2
  float si[2];
  #pragma unroll
  for (int g=0; g<2; ++g){
    float sm = ssum[g];
    sm += __shfl_xor(sm, 16);
    sm += __shfl_xor(sm, 32);
    si[g] = 1.0f / sm;          // uniform across l4 for each l15
    float invr[4];
    #pragma unroll
    for (int i=0;i<4;i++) invr[i] = __shfl(si[g], 4*l4+i);
    float* ob = Out + ((long)(bh*SQ) + rbase + 16*g)*DD;
    #pragma unroll
    for (int df=0;df<8;df++){
      #pragma unroll
      for (int i=0;i<4;i++)
        ob[(4*l4+i)*DD + 16*df + l15] = oacc[g][df][i]*invr[i];
    }
  }

  // ======================= PASS 2 =======================
  float* Wbase = Wout + (long)bh*SQ*SQ;
  __syncthreads();
  stageK(0, 0);
  __syncthreads();
  cur = 0;
  for (int kt=0; kt<nktA; ++kt){
    if (kt+1 < nktA) stageK(cur^1, kt+1);

    if (kt < myNkt){
      f32x4 sacc[2][4] = {{z4,z4,z4,z4},{z4,z4,z4,z4}};
      {
        const char* kbase = &Kt[cur][0] + l15*256;
        __builtin_amdgcn_s_setprio(1);
        #pragma unroll
        for (int cf=0;cf<4;cf++){
          #pragma unroll
          for (int kk=0;kk<4;kk++){
            bf16x8 kb = *(const bf16x8*)(kbase + cf*4096 + ((64*kk+16*l4) ^ swz));
            sacc[0][cf] = __builtin_amdgcn_mfma_f32_16x16x32_bf16(kb, qa[0][kk], sacc[0][cf], 0,0,0);
            sacc[1][cf] = __builtin_amdgcn_mfma_f32_16x16x32_bf16(kb, qa[1][kk], sacc[1][cf], 0,0,0);
          }
        }
        __builtin_amdgcn_s_setprio(0);
      }
      const int k0 = kt*64;
      if (kt < qt){   // full tile
        #pragma unroll
        for (int g=0; g<2; ++g){
          float* wrow = Wbase + (long)(rbase + 16*g + l15)*SQ;
          #pragma unroll
          for (int cf=0;cf<4;cf++){
            const int tok0 = k0 + 16*cf + 4*l4;
            float4 wv;
            wv.x = exp2f(sacc[g][cf][0]*SC2)*si[g];
            wv.y = exp2f(sacc[g][cf][1]*SC2)*si[g];
            wv.z = exp2f(sacc[g][cf][2]*SC2)*si[g];
            wv.w = exp2f(sacc[g][cf][3]*SC2)*si[g];
            *(float4*)(wrow + tok0) = wv;
          }
        }
      } else {        // diagonal tile
        #pragma unroll
        for (int g=0; g<2; ++g){
          const int qrow = rbase + 16*g + l15;
          float* wrow = Wbase + (long)qrow*SQ;
          #pragma unroll
          for (int cf=0;cf<4;cf++){
            const int tok0 = k0 + 16*cf + 4*l4;
            float4 wv;
            wv.x = (tok0+0 <= qrow) ? exp2f(sacc[g][cf][0]*SC2)*si[g] : 0.f;
            wv.y = (tok0+1 <= qrow) ? exp2f(sacc[g][cf][1]*SC2)*si[g] : 0.f;
            wv.z = (tok0+2 <= qrow) ? exp2f(sacc[g][cf][2]*SC2)*si[g] : 0.f;
            wv.w = (tok0+3 <= qrow) ? exp2f(sacc[g][cf][3]*SC2)*si[g] : 0.f;
            *(float4*)(wrow + tok0) = wv;
          }
        }
      }
    }
    __syncthreads();
    cur ^= 1;
  }

  // zero-fill fully-masked columns [myNkt*64, 2048) for the wave's 32 rows
  const int z0 = myNkt*64;
  if (z0 < SQ){
    const float4 zz = {0.f,0.f,0.f,0.f};
    for (int rr=0;rr<32;rr++){
      float* row = Wbase + (long)(rbase + rr)*SQ;
      for (int c = z0 + 4*lane; c < SQ; c += 256)
        *(float4*)(row + c) = zz;
    }
  }
}

extern "C" void kernel_launch(void* const* d_in, const int* in_sizes, int n_in,
                              void* d_out, int out_size, void* d_ws, size_t ws_size,
                              hipStream_t stream) {
  const float* Q = (const float*)d_in[0];
  const float* K = (const float*)d_in[1];
  const float* V = (const float*)d_in[2];
  float* Out = (float*)d_out;
  float* Wout = (float*)d_out + (size_t)BHN*SQ*DD;
  char* dqK  = (char*)d_ws;                                // 16 MB
  char* dqVt = (char*)d_ws + (size_t)BHN*SQ*DD*2;          // 16 MB

  qd_kernel<<<BHN*32, 256, 0, stream>>>(K, V, dqK, dqVt);
  attn_fused<<<512, 256, 0, stream>>>(Q, dqK, dqVt, Out, Wout);
}